// Round 2
// baseline (624.855 us; speedup 1.0000x reference)
//
#include <hip/hip_runtime.h>
#include <hip/hip_bf16.h>

// textPCNN fused: fp32 inputs. embed-gather(+fp32->bf16 cvt) -> conv GEMM
// (mfma_f32_16x16x32_bf16) -> piecewise max-pool (pool raw acc; tanh after,
// since tanh is monotonic) -> 1536x53 out-GEMM. One block per sentence.
// N=1024, L=128, D=400, K=1200, NF=512, LP=126, C=53.
// conv_w is pre-converted fp32->bf16 into d_ws by convert_convw each launch.

#define XSTRIDE 424     // LDS x-row stride in bf16 elems (848 B, 16B-aligned)
#define LPV 126
#define NC 53

typedef __attribute__((ext_vector_type(8))) short short8;
typedef __attribute__((ext_vector_type(4))) float floatx4;

__device__ __forceinline__ unsigned short f2bf_rne(float x) {
    unsigned u = __float_as_uint(x);
    u += 0x7fffu + ((u >> 16) & 1u);   // round-to-nearest-even (inputs finite)
    return (unsigned short)(u >> 16);
}

__global__ void __launch_bounds__(1024)
convert_convw(const float* __restrict__ src, unsigned short* __restrict__ dst) {
    int i = blockIdx.x * 1024 + threadIdx.x;
    if (i < 512 * 1200) dst[i] = f2bf_rne(src[i]);
}

extern "C" __global__ void __launch_bounds__(512, 2)
pcnn_fused(const int* __restrict__ tokens, const int* __restrict__ pf1,
           const int* __restrict__ pf2, const int* __restrict__ epos,
           const float* __restrict__ wordvec,
           const float* __restrict__ pf1e,
           const float* __restrict__ pf2e,
           const unsigned short* __restrict__ convwb,   // bf16 [512][1200] in ws
           const float* __restrict__ convb,
           const float* __restrict__ outw,
           const float* __restrict__ outb,
           float* __restrict__ out)
{
    extern __shared__ char smem[];
    unsigned short* xl = (unsigned short*)smem;          // 130*424 ush = 110240 B
    float* feat = (float*)(smem + 110240);               // 1536 f = 6144 B
    float* red  = (float*)(smem + 110240 + 6144);        // 512 f  = 2048 B

    const int n    = blockIdx.x;
    const int tid  = threadIdx.x;
    const int lane = tid & 63;
    const int wv   = tid >> 6;

    // zero pad rows 128/129 cols [0,400) so t=126,127 windows read finite zeros
    for (int i = tid; i < 800; i += 512) {
        int r = i >= 400, c = i - r * 400;
        xl[(128 + r) * XSTRIDE + c] = 0;
    }

    // ---- gather + fp32->bf16 convert: wave wv stages rows [16wv,16wv+16) ----
    {
        const float2* wv2 = (const float2*)wordvec;   // 150 float2 per row
        const float2* p12 = (const float2*)pf1e;      // 25 float2 per row
        const float2* p22 = (const float2*)pf2e;
        for (int i = 0; i < 16; ++i) {
            int l = wv * 16 + i, base = n * 128 + l;
            int tok = tokens[base], i1 = pf1[base], i2 = pf2[base];
            ushort2* dst = (ushort2*)(xl + l * XSTRIDE);
            const float2* ws = wv2 + (long)tok * 150;
            for (int j = lane; j < 150; j += 64) {
                float2 v = ws[j];
                dst[j] = make_ushort2(f2bf_rne(v.x), f2bf_rne(v.y));
            }
            if (lane < 25) {
                float2 v = p12[i1 * 25 + lane];
                dst[150 + lane] = make_ushort2(f2bf_rne(v.x), f2bf_rne(v.y));
                float2 w = p22[i2 * 25 + lane];
                dst[175 + lane] = make_ushort2(f2bf_rne(w.x), f2bf_rne(w.y));
            }
        }
    }
    __syncthreads();

    // ---- conv GEMM: C[128 t x 512 f]; wave wv owns f in [64wv, 64wv+64) ----
    // A[t][k] = xl[t + k/400][k%400] (window of 3 rows); B^T row f, bf16 in ws.
    const int col = lane & 15;   // A row-in-tile / B row-in-tile / C col
    const int kq  = lane >> 4;   // k-quad: k offset 8*kq; C row = 4*kq + r

    const floatx4 fz = {0.f, 0.f, 0.f, 0.f};
    floatx4 acc[8][4];   // [mt][jt]
    #pragma unroll
    for (int mt = 0; mt < 8; ++mt)
        #pragma unroll
        for (int jt = 0; jt < 4; ++jt) acc[mt][jt] = fz;

    int ck   = kq * 8;                       // k mod 400 for this lane
    int aoff = col * XSTRIDE + kq * 8;       // elem offset of A frag (row mt=0)
    const unsigned short* bptr = convwb + (wv * 64 + col) * 1200 + kq * 8;

    #pragma unroll 1
    for (int kt = 0; kt < 37; ++kt) {        // K = 37*32 + 16 remainder
        short8 a[8], b[4];
        #pragma unroll
        for (int mt = 0; mt < 8; ++mt)
            a[mt] = *(const short8*)(xl + aoff + mt * (16 * XSTRIDE));
        #pragma unroll
        for (int jt = 0; jt < 4; ++jt)
            b[jt] = *(const short8*)(bptr + jt * (16 * 1200));
        #pragma unroll
        for (int mt = 0; mt < 8; ++mt)
            #pragma unroll
            for (int jt = 0; jt < 4; ++jt)
                acc[mt][jt] = __builtin_amdgcn_mfma_f32_16x16x32_bf16(
                    a[mt], b[jt], acc[mt][jt], 0, 0, 0);
        ck += 32; aoff += 32; bptr += 32;
        if (ck >= 400) { ck -= 400; aoff += XSTRIDE - 400; }
    }
    {   // remainder k0=1184..1199: only kq<2 lanes carry real k
        const short8 z8 = {0, 0, 0, 0, 0, 0, 0, 0};
        short8 a[8], b[4];
        #pragma unroll
        for (int mt = 0; mt < 8; ++mt) a[mt] = z8;
        #pragma unroll
        for (int jt = 0; jt < 4; ++jt) b[jt] = z8;
        if (kq < 2) {
            #pragma unroll
            for (int mt = 0; mt < 8; ++mt)
                a[mt] = *(const short8*)(xl + aoff + mt * (16 * XSTRIDE));
            #pragma unroll
            for (int jt = 0; jt < 4; ++jt)
                b[jt] = *(const short8*)(bptr + jt * (16 * 1200));
        }
        #pragma unroll
        for (int mt = 0; mt < 8; ++mt)
            #pragma unroll
            for (int jt = 0; jt < 4; ++jt)
                acc[mt][jt] = __builtin_amdgcn_mfma_f32_16x16x32_bf16(
                    a[mt], b[jt], acc[mt][jt], 0, 0, 0);
    }

    // ---- epilogue: pool raw acc over 3 segments, reduce across kq lanes ----
    const int p1 = epos[2 * n], p2 = epos[2 * n + 1];
    #pragma unroll 1
    for (int jt = 0; jt < 4; ++jt) {
        float m0 = -1e30f, m1 = -1e30f, m2 = -1e30f;
        #pragma unroll
        for (int mt = 0; mt < 8; ++mt) {
            #pragma unroll
            for (int r = 0; r < 4; ++r) {
                int t = mt * 16 + kq * 4 + r;   // C/D row mapping
                float v = acc[mt][jt][r];
                if (t < LPV) {
                    if (t <= p1) m0 = fmaxf(m0, v);
                    if (t >= p1 && t <= p2) m1 = fmaxf(m1, v);
                    if (t >= p2) m2 = fmaxf(m2, v);
                }
            }
        }
        // lanes sharing col differ in kq (xor 16, 32): reduce t-coverage
        m0 = fmaxf(m0, __shfl_xor(m0, 16)); m0 = fmaxf(m0, __shfl_xor(m0, 32));
        m1 = fmaxf(m1, __shfl_xor(m1, 16)); m1 = fmaxf(m1, __shfl_xor(m1, 32));
        m2 = fmaxf(m2, __shfl_xor(m2, 16)); m2 = fmaxf(m2, __shfl_xor(m2, 32));
        if (kq == 0) {
            int f = wv * 64 + jt * 16 + col;
            float bias = convb[f];
            // tanh monotonic: max(tanh(x+b)) == tanh(max(x)+b); segs nonempty
            feat[3 * f + 0] = tanhf(m0 + bias);
            feat[3 * f + 1] = tanhf(m1 + bias);
            feat[3 * f + 2] = tanhf(m2 + bias);
        }
    }
    __syncthreads();

    // ---- out GEMM: out[n,c] = feat . out_w[:,c] + out_b[c], fp32 ----
    {
        int c = tid & 63;
        int chunk = tid >> 6;          // 8 chunks x 192 j
        float partial = 0.f;
        if (c < NC) {
            int j0 = chunk * 192;
            #pragma unroll 4
            for (int j = j0; j < j0 + 192; ++j)
                partial += feat[j] * outw[j * 53 + c];
        }
        red[tid] = partial;
        __syncthreads();
        if (tid < NC) {
            float s = outb[tid];
            #pragma unroll
            for (int ch = 0; ch < 8; ++ch) s += red[ch * 64 + tid];
            out[n * 53 + tid] = s;
        }
    }
}

extern "C" void kernel_launch(void* const* d_in, const int* in_sizes, int n_in,
                              void* d_out, int out_size, void* d_ws, size_t ws_size,
                              hipStream_t stream) {
    (void)in_sizes; (void)n_in; (void)ws_size; (void)out_size;
    const int* tokens = (const int*)d_in[0];
    const int* pf1    = (const int*)d_in[1];
    const int* pf2    = (const int*)d_in[2];
    const int* epos   = (const int*)d_in[3];
    const float* wordvec = (const float*)d_in[4];
    const float* pf1e    = (const float*)d_in[5];
    const float* pf2e    = (const float*)d_in[6];
    const float* convw   = (const float*)d_in[7];
    const float* convb   = (const float*)d_in[8];
    const float* outw    = (const float*)d_in[9];
    const float* outb    = (const float*)d_in[10];
    float* out = (float*)d_out;

    unsigned short* convwb = (unsigned short*)d_ws;   // 512*1200 bf16 = 1.23 MB

    convert_convw<<<dim3(600), dim3(1024), 0, stream>>>(convw, convwb);

    const size_t lds_bytes = 110240 + 6144 + 2048;    // 118432
    pcnn_fused<<<dim3(1024), dim3(512), lds_bytes, stream>>>(
        tokens, pf1, pf2, epos, wordvec, pf1e, pf2e, convwb,
        convb, outw, outb, out);
}

// Round 3
// 501.203 us; speedup vs baseline: 1.2467x; 1.2467x over previous
//
#include <hip/hip_runtime.h>
#include <hip/hip_bf16.h>

// textPCNN fused: fp32 inputs. embed-gather(+fp32->bf16 cvt) -> conv GEMM
// (mfma_f32_16x16x32_bf16) -> piecewise max-pool (pool raw acc; tanh after,
// since tanh is monotonic) -> 1536x53 out-GEMM. One block per sentence.
// N=1024, L=128, D=400, K=1200, NF=512, LP=126, C=53.
// conv_w is pre-converted fp32->bf16 into d_ws by convert_convw each launch.
// R2 fix: epilogue jt-loop FULLY UNROLLED -- round 1's `#pragma unroll 1`
// made acc[] runtime-indexed -> compiler put the whole accumulator in
// scratch (VGPR_Count=96, WRITE_SIZE=615MB of spill traffic, 495us).

#define XSTRIDE 424     // LDS x-row stride in bf16 elems (848 B, 16B-aligned)
#define LPV 126
#define NC 53

typedef __attribute__((ext_vector_type(8))) short short8;
typedef __attribute__((ext_vector_type(4))) float floatx4;

__device__ __forceinline__ unsigned short f2bf_rne(float x) {
    unsigned u = __float_as_uint(x);
    u += 0x7fffu + ((u >> 16) & 1u);   // round-to-nearest-even (inputs finite)
    return (unsigned short)(u >> 16);
}

__global__ void __launch_bounds__(1024)
convert_convw(const float* __restrict__ src, unsigned short* __restrict__ dst) {
    int i = blockIdx.x * 1024 + threadIdx.x;
    if (i < 512 * 1200) dst[i] = f2bf_rne(src[i]);
}

extern "C" __global__ void __launch_bounds__(512, 2)
pcnn_fused(const int* __restrict__ tokens, const int* __restrict__ pf1,
           const int* __restrict__ pf2, const int* __restrict__ epos,
           const float* __restrict__ wordvec,
           const float* __restrict__ pf1e,
           const float* __restrict__ pf2e,
           const unsigned short* __restrict__ convwb,   // bf16 [512][1200] in ws
           const float* __restrict__ convb,
           const float* __restrict__ outw,
           const float* __restrict__ outb,
           float* __restrict__ out)
{
    extern __shared__ char smem[];
    unsigned short* xl = (unsigned short*)smem;          // 130*424 ush = 110240 B
    float* feat = (float*)(smem + 110240);               // 1536 f = 6144 B
    float* red  = (float*)(smem + 110240 + 6144);        // 512 f  = 2048 B

    const int n    = blockIdx.x;
    const int tid  = threadIdx.x;
    const int lane = tid & 63;
    const int wv   = tid >> 6;

    // zero pad rows 128/129 cols [0,400) so t=126,127 windows read finite zeros
    for (int i = tid; i < 800; i += 512) {
        int r = i >= 400, c = i - r * 400;
        xl[(128 + r) * XSTRIDE + c] = 0;
    }

    // ---- gather + fp32->bf16 convert: wave wv stages rows [16wv,16wv+16) ----
    {
        const float4* wv4 = (const float4*)wordvec;   // 75 float4 per row
        const float2* p12 = (const float2*)pf1e;      // 25 float2 per row
        const float2* p22 = (const float2*)pf2e;
        for (int i = 0; i < 16; ++i) {
            int l = wv * 16 + i, base = n * 128 + l;
            int tok = tokens[base], i1 = pf1[base], i2 = pf2[base];
            const float4* ws = wv4 + (long)tok * 75;
            ushort4* dst4 = (ushort4*)(xl + l * XSTRIDE);
            for (int j = lane; j < 75; j += 64) {
                float4 v = ws[j];
                dst4[j] = make_ushort4(f2bf_rne(v.x), f2bf_rne(v.y),
                                       f2bf_rne(v.z), f2bf_rne(v.w));
            }
            if (lane < 25) {
                ushort2* dst2 = (ushort2*)(xl + l * XSTRIDE);
                float2 v = p12[i1 * 25 + lane];
                dst2[150 + lane] = make_ushort2(f2bf_rne(v.x), f2bf_rne(v.y));
                float2 w = p22[i2 * 25 + lane];
                dst2[175 + lane] = make_ushort2(f2bf_rne(w.x), f2bf_rne(w.y));
            }
        }
    }
    __syncthreads();

    // ---- conv GEMM: C[128 t x 512 f]; wave wv owns f in [64wv, 64wv+64) ----
    // A[t][k] = xl[t + k/400][k%400] (window of 3 rows); B^T row f, bf16 in ws.
    const int col = lane & 15;   // A row-in-tile / B row-in-tile / C col
    const int kq  = lane >> 4;   // k-quad: k offset 8*kq; C row = 4*kq + r

    const floatx4 fz = {0.f, 0.f, 0.f, 0.f};
    floatx4 acc[8][4];   // [mt][jt]
    #pragma unroll
    for (int mt = 0; mt < 8; ++mt)
        #pragma unroll
        for (int jt = 0; jt < 4; ++jt) acc[mt][jt] = fz;

    int ck   = kq * 8;                       // k mod 400 for this lane
    int aoff = col * XSTRIDE + kq * 8;       // elem offset of A frag (row mt=0)
    const unsigned short* bptr = convwb + (wv * 64 + col) * 1200 + kq * 8;

    #pragma unroll 1
    for (int kt = 0; kt < 37; ++kt) {        // K = 37*32 + 16 remainder
        short8 a[8], b[4];
        #pragma unroll
        for (int mt = 0; mt < 8; ++mt)
            a[mt] = *(const short8*)(xl + aoff + mt * (16 * XSTRIDE));
        #pragma unroll
        for (int jt = 0; jt < 4; ++jt)
            b[jt] = *(const short8*)(bptr + jt * (16 * 1200));
        #pragma unroll
        for (int mt = 0; mt < 8; ++mt)
            #pragma unroll
            for (int jt = 0; jt < 4; ++jt)
                acc[mt][jt] = __builtin_amdgcn_mfma_f32_16x16x32_bf16(
                    a[mt], b[jt], acc[mt][jt], 0, 0, 0);
        ck += 32; aoff += 32; bptr += 32;
        if (ck >= 400) { ck -= 400; aoff += XSTRIDE - 400; }
    }
    {   // remainder k0=1184..1199: only kq<2 lanes carry real k
        const short8 z8 = {0, 0, 0, 0, 0, 0, 0, 0};
        short8 a[8], b[4];
        #pragma unroll
        for (int mt = 0; mt < 8; ++mt) a[mt] = z8;
        #pragma unroll
        for (int jt = 0; jt < 4; ++jt) b[jt] = z8;
        if (kq < 2) {
            #pragma unroll
            for (int mt = 0; mt < 8; ++mt)
                a[mt] = *(const short8*)(xl + aoff + mt * (16 * XSTRIDE));
            #pragma unroll
            for (int jt = 0; jt < 4; ++jt)
                b[jt] = *(const short8*)(bptr + jt * (16 * 1200));
        }
        #pragma unroll
        for (int mt = 0; mt < 8; ++mt)
            #pragma unroll
            for (int jt = 0; jt < 4; ++jt)
                acc[mt][jt] = __builtin_amdgcn_mfma_f32_16x16x32_bf16(
                    a[mt], b[jt], acc[mt][jt], 0, 0, 0);
    }

    // ---- epilogue: pool raw acc over 3 segments, reduce across kq lanes ----
    // FULLY unrolled (no runtime indexing into acc -> keeps acc in registers)
    const int p1 = epos[2 * n], p2 = epos[2 * n + 1];
    #pragma unroll
    for (int jt = 0; jt < 4; ++jt) {
        float m0 = -1e30f, m1 = -1e30f, m2 = -1e30f;
        #pragma unroll
        for (int mt = 0; mt < 8; ++mt) {
            #pragma unroll
            for (int r = 0; r < 4; ++r) {
                int t = mt * 16 + kq * 4 + r;   // C/D row mapping
                float v = acc[mt][jt][r];
                if (t < LPV) {
                    if (t <= p1) m0 = fmaxf(m0, v);
                    if (t >= p1 && t <= p2) m1 = fmaxf(m1, v);
                    if (t >= p2) m2 = fmaxf(m2, v);
                }
            }
        }
        // lanes sharing col differ in kq (xor 16, 32): reduce t-coverage
        m0 = fmaxf(m0, __shfl_xor(m0, 16)); m0 = fmaxf(m0, __shfl_xor(m0, 32));
        m1 = fmaxf(m1, __shfl_xor(m1, 16)); m1 = fmaxf(m1, __shfl_xor(m1, 32));
        m2 = fmaxf(m2, __shfl_xor(m2, 16)); m2 = fmaxf(m2, __shfl_xor(m2, 32));
        if (kq == 0) {
            int f = wv * 64 + jt * 16 + col;
            float bias = convb[f];
            // tanh monotonic: max(tanh(x+b)) == tanh(max(x)+b); segs nonempty
            feat[3 * f + 0] = tanhf(m0 + bias);
            feat[3 * f + 1] = tanhf(m1 + bias);
            feat[3 * f + 2] = tanhf(m2 + bias);
        }
    }
    __syncthreads();

    // ---- out GEMM: out[n,c] = feat . out_w[:,c] + out_b[c], fp32 ----
    {
        int c = tid & 63;
        int chunk = tid >> 6;          // 8 chunks x 192 j
        float partial = 0.f;
        if (c < NC) {
            int j0 = chunk * 192;
            #pragma unroll 4
            for (int j = j0; j < j0 + 192; ++j)
                partial += feat[j] * outw[j * 53 + c];
        }
        red[tid] = partial;
        __syncthreads();
        if (tid < NC) {
            float s = outb[tid];
            #pragma unroll
            for (int ch = 0; ch < 8; ++ch) s += red[ch * 64 + tid];
            out[n * 53 + tid] = s;
        }
    }
}

extern "C" void kernel_launch(void* const* d_in, const int* in_sizes, int n_in,
                              void* d_out, int out_size, void* d_ws, size_t ws_size,
                              hipStream_t stream) {
    (void)in_sizes; (void)n_in; (void)ws_size; (void)out_size;
    const int* tokens = (const int*)d_in[0];
    const int* pf1    = (const int*)d_in[1];
    const int* pf2    = (const int*)d_in[2];
    const int* epos   = (const int*)d_in[3];
    const float* wordvec = (const float*)d_in[4];
    const float* pf1e    = (const float*)d_in[5];
    const float* pf2e    = (const float*)d_in[6];
    const float* convw   = (const float*)d_in[7];
    const float* convb   = (const float*)d_in[8];
    const float* outw    = (const float*)d_in[9];
    const float* outb    = (const float*)d_in[10];
    float* out = (float*)d_out;

    unsigned short* convwb = (unsigned short*)d_ws;   // 512*1200 bf16 = 1.23 MB

    convert_convw<<<dim3(600), dim3(1024), 0, stream>>>(convw, convwb);

    const size_t lds_bytes = 110240 + 6144 + 2048;    // 118432
    pcnn_fused<<<dim3(1024), dim3(512), lds_bytes, stream>>>(
        tokens, pf1, pf2, epos, wordvec, pf1e, pf2e, convwb,
        convb, outw, outb, out);
}

// Round 4
// 499.659 us; speedup vs baseline: 1.2506x; 1.0031x over previous
//
#include <hip/hip_runtime.h>
#include <hip/hip_bf16.h>

// textPCNN, split pipeline (R4):
//  K0 convert_convw: conv_w fp32 -> bf16 into ws           (1.23 MB)
//  K1 gather_stage : embedding gather + fp32->bf16, x -> ws (105 MB, bf16)
//  K2 pcnn_gemm    : stage x ws->LDS (contiguous, pipelined) -> conv GEMM
//                    (mfma 16x16x32 bf16) -> pool raw acc -> tanh -> out GEMM.
// R3 post-mortem: fused kernel 358us, MfmaUtil 19%, HBM 3.8%, occupancy 23%;
// serial per-wave gather + un-attributable latency. Split removes the
// dependent-chain gather from the GEMM kernel and gives per-phase timing.
// GEMM K-loop/epilogue byte-identical to R3 for attribution.

#define XSTRIDE 424     // LDS x-row stride in bf16 elems (848 B = 53 short8)
#define LPV 126
#define NC 53

typedef __attribute__((ext_vector_type(8))) short short8;
typedef __attribute__((ext_vector_type(4))) float floatx4;

__device__ __forceinline__ unsigned short f2bf_rne(float x) {
    unsigned u = __float_as_uint(x);
    u += 0x7fffu + ((u >> 16) & 1u);   // round-to-nearest-even (inputs finite)
    return (unsigned short)(u >> 16);
}

__global__ void __launch_bounds__(1024)
convert_convw(const float* __restrict__ src, unsigned short* __restrict__ dst) {
    int i = blockIdx.x * 1024 + threadIdx.x;
    if (i < 512 * 1200) dst[i] = f2bf_rne(src[i]);
}

// K1: block n gathers sentence n's 128 rows of x (400 bf16 each) into ws.
// Flat loop over 128 rows x 200 ushort2-chunks; all iterations independent
// -> deep vmcnt pipelining, coalesced 4B stores.
__global__ void __launch_bounds__(512)
gather_stage(const int* __restrict__ tokens, const int* __restrict__ pf1,
             const int* __restrict__ pf2,
             const float* __restrict__ wordvec,
             const float* __restrict__ pf1e,
             const float* __restrict__ pf2e,
             unsigned short* __restrict__ xws)   // [1024][128][400] bf16
{
    const int n = blockIdx.x, tid = threadIdx.x;
    const float2* wv2 = (const float2*)wordvec;   // 150 float2 per row
    const float2* p12 = (const float2*)pf1e;      // 25 float2 per row
    const float2* p22 = (const float2*)pf2e;
    ushort2* dst2 = (ushort2*)(xws + n * 128 * 400);
    #pragma unroll 4
    for (int i = tid; i < 128 * 200; i += 512) {
        int row = i / 200, c = i - row * 200;
        int base = n * 128 + row;
        float2 v;
        if (c < 150)      v = wv2[(long)tokens[base] * 150 + c];
        else if (c < 175) v = p12[pf1[base] * 25 + (c - 150)];
        else              v = p22[pf2[base] * 25 + (c - 175)];
        dst2[row * 200 + c] = make_ushort2(f2bf_rne(v.x), f2bf_rne(v.y));
    }
}

extern "C" __global__ void __launch_bounds__(512, 2)
pcnn_gemm(const int* __restrict__ epos,
          const unsigned short* __restrict__ xws,      // bf16 [1024][128][400]
          const unsigned short* __restrict__ convwb,   // bf16 [512][1200]
          const float* __restrict__ convb,
          const float* __restrict__ outw,
          const float* __restrict__ outb,
          float* __restrict__ out)
{
    extern __shared__ char smem[];
    unsigned short* xl = (unsigned short*)smem;          // 130*424 ush = 110240 B
    float* feat = (float*)(smem + 110240);               // 1536 f = 6144 B
    float* red  = (float*)(smem + 110240 + 6144);        // 512 f  = 2048 B

    const int n    = blockIdx.x;
    const int tid  = threadIdx.x;
    const int lane = tid & 63;
    const int wv   = tid >> 6;

    // ---- stage x: ws -> LDS (stride 400 -> 424), 16B chunks, independent ----
    {
        const short8* src = (const short8*)(xws + (long)n * 128 * 400); // 50/row
        short8* dst = (short8*)xl;                                      // 53/row
        #pragma unroll 4
        for (int i = tid; i < 128 * 50; i += 512) {
            int row = i / 50, c = i - row * 50;
            dst[row * 53 + c] = src[i];
        }
        const short8 z8 = {0, 0, 0, 0, 0, 0, 0, 0};
        for (int i = tid; i < 100; i += 512) {           // zero rows 128,129
            int row = 128 + i / 50, c = i % 50;
            dst[row * 53 + c] = z8;
        }
    }
    __syncthreads();

    // ---- conv GEMM: C[128 t x 512 f]; wave wv owns f in [64wv, 64wv+64) ----
    // A[t][k] = xl[t + k/400][k%400] (window of 3 rows); B^T row f (bf16, ws).
    const int col = lane & 15;   // A row-in-tile / B row-in-tile / C col
    const int kq  = lane >> 4;   // k-quad: k offset 8*kq; C row = 4*kq + r

    const floatx4 fz = {0.f, 0.f, 0.f, 0.f};
    floatx4 acc[8][4];   // [mt][jt]
    #pragma unroll
    for (int mt = 0; mt < 8; ++mt)
        #pragma unroll
        for (int jt = 0; jt < 4; ++jt) acc[mt][jt] = fz;

    int ck   = kq * 8;                       // k mod 400 for this lane
    int aoff = col * XSTRIDE + kq * 8;       // elem offset of A frag (row mt=0)
    const unsigned short* bptr = convwb + (wv * 64 + col) * 1200 + kq * 8;

    #pragma unroll 1
    for (int kt = 0; kt < 37; ++kt) {        // K = 37*32 + 16 remainder
        short8 a[8], b[4];
        #pragma unroll
        for (int mt = 0; mt < 8; ++mt)
            a[mt] = *(const short8*)(xl + aoff + mt * (16 * XSTRIDE));
        #pragma unroll
        for (int jt = 0; jt < 4; ++jt)
            b[jt] = *(const short8*)(bptr + jt * (16 * 1200));
        #pragma unroll
        for (int mt = 0; mt < 8; ++mt)
            #pragma unroll
            for (int jt = 0; jt < 4; ++jt)
                acc[mt][jt] = __builtin_amdgcn_mfma_f32_16x16x32_bf16(
                    a[mt], b[jt], acc[mt][jt], 0, 0, 0);
        ck += 32; aoff += 32; bptr += 32;
        if (ck >= 400) { ck -= 400; aoff += XSTRIDE - 400; }
    }
    {   // remainder k0=1184..1199: only kq<2 lanes carry real k
        const short8 z8 = {0, 0, 0, 0, 0, 0, 0, 0};
        short8 a[8], b[4];
        #pragma unroll
        for (int mt = 0; mt < 8; ++mt) a[mt] = z8;
        #pragma unroll
        for (int jt = 0; jt < 4; ++jt) b[jt] = z8;
        if (kq < 2) {
            #pragma unroll
            for (int mt = 0; mt < 8; ++mt)
                a[mt] = *(const short8*)(xl + aoff + mt * (16 * XSTRIDE));
            #pragma unroll
            for (int jt = 0; jt < 4; ++jt)
                b[jt] = *(const short8*)(bptr + jt * (16 * 1200));
        }
        #pragma unroll
        for (int mt = 0; mt < 8; ++mt)
            #pragma unroll
            for (int jt = 0; jt < 4; ++jt)
                acc[mt][jt] = __builtin_amdgcn_mfma_f32_16x16x32_bf16(
                    a[mt], b[jt], acc[mt][jt], 0, 0, 0);
    }

    // ---- epilogue: pool raw acc over 3 segments, reduce across kq lanes ----
    const int p1 = epos[2 * n], p2 = epos[2 * n + 1];
    #pragma unroll
    for (int jt = 0; jt < 4; ++jt) {
        float m0 = -1e30f, m1 = -1e30f, m2 = -1e30f;
        #pragma unroll
        for (int mt = 0; mt < 8; ++mt) {
            #pragma unroll
            for (int r = 0; r < 4; ++r) {
                int t = mt * 16 + kq * 4 + r;   // C/D row mapping
                float v = acc[mt][jt][r];
                if (t < LPV) {
                    if (t <= p1) m0 = fmaxf(m0, v);
                    if (t >= p1 && t <= p2) m1 = fmaxf(m1, v);
                    if (t >= p2) m2 = fmaxf(m2, v);
                }
            }
        }
        // lanes sharing col differ in kq (xor 16, 32): reduce t-coverage
        m0 = fmaxf(m0, __shfl_xor(m0, 16)); m0 = fmaxf(m0, __shfl_xor(m0, 32));
        m1 = fmaxf(m1, __shfl_xor(m1, 16)); m1 = fmaxf(m1, __shfl_xor(m1, 32));
        m2 = fmaxf(m2, __shfl_xor(m2, 16)); m2 = fmaxf(m2, __shfl_xor(m2, 32));
        if (kq == 0) {
            int f = wv * 64 + jt * 16 + col;
            float bias = convb[f];
            // tanh monotonic: max(tanh(x+b)) == tanh(max(x)+b); segs nonempty
            feat[3 * f + 0] = tanhf(m0 + bias);
            feat[3 * f + 1] = tanhf(m1 + bias);
            feat[3 * f + 2] = tanhf(m2 + bias);
        }
    }
    __syncthreads();

    // ---- out GEMM: out[n,c] = feat . out_w[:,c] + out_b[c], fp32 ----
    {
        int c = tid & 63;
        int chunk = tid >> 6;          // 8 chunks x 192 j
        float partial = 0.f;
        if (c < NC) {
            int j0 = chunk * 192;
            #pragma unroll 4
            for (int j = j0; j < j0 + 192; ++j)
                partial += feat[j] * outw[j * 53 + c];
        }
        red[tid] = partial;
        __syncthreads();
        if (tid < NC) {
            float s = outb[tid];
            #pragma unroll
            for (int ch = 0; ch < 8; ++ch) s += red[ch * 64 + tid];
            out[n * 53 + tid] = s;
        }
    }
}

extern "C" void kernel_launch(void* const* d_in, const int* in_sizes, int n_in,
                              void* d_out, int out_size, void* d_ws, size_t ws_size,
                              hipStream_t stream) {
    (void)in_sizes; (void)n_in; (void)ws_size; (void)out_size;
    const int* tokens = (const int*)d_in[0];
    const int* pf1    = (const int*)d_in[1];
    const int* pf2    = (const int*)d_in[2];
    const int* epos   = (const int*)d_in[3];
    const float* wordvec = (const float*)d_in[4];
    const float* pf1e    = (const float*)d_in[5];
    const float* pf2e    = (const float*)d_in[6];
    const float* convw   = (const float*)d_in[7];
    const float* convb   = (const float*)d_in[8];
    const float* outw    = (const float*)d_in[9];
    const float* outb    = (const float*)d_in[10];
    float* out = (float*)d_out;

    // ws layout: [0, 1228800) convwb bf16; [1228800, +104857600) xws bf16
    unsigned short* convwb = (unsigned short*)d_ws;
    unsigned short* xws    = (unsigned short*)((char*)d_ws + 1228800);

    convert_convw<<<dim3(600), dim3(1024), 0, stream>>>(convw, convwb);
    gather_stage<<<dim3(1024), dim3(512), 0, stream>>>(
        tokens, pf1, pf2, wordvec, pf1e, pf2e, xws);

    const size_t lds_bytes = 110240 + 6144 + 2048;    // 118432
    pcnn_gemm<<<dim3(1024), dim3(512), lds_bytes, stream>>>(
        epos, xws, convwb, convb, outw, outb, out);
}

// Round 5
// 467.013 us; speedup vs baseline: 1.3380x; 1.0699x over previous
//
#include <hip/hip_runtime.h>
#include <hip/hip_bf16.h>

// textPCNN fused (R5): flat embed-gather(+fp32->bf16) into LDS -> conv GEMM
// (mfma 16x16x32 bf16, barrier-free K-loop, B register-prefetch) -> pool raw
// acc -> tanh -> out GEMM. One block per sentence.
// R4 attribution: standalone gather 240us (105MB ws round-trip is pure loss;
// R3 fused gather was ~104us) -> re-fuse with flat independent gather.
// GEMM 254us @ MfmaUtil 28% = L2 B-load latency unhidden at 2 waves/SIMD ->
// one-iteration register prefetch of B (+16 VGPR: 224->240, still <=256, no
// occupancy change).

#define XSTRIDE 424     // LDS x-row stride in bf16 elems (848 B = 53 short8)
#define LPV 126
#define NC 53

typedef __attribute__((ext_vector_type(8))) short short8;
typedef __attribute__((ext_vector_type(4))) float floatx4;

__device__ __forceinline__ unsigned short f2bf_rne(float x) {
    unsigned u = __float_as_uint(x);
    u += 0x7fffu + ((u >> 16) & 1u);   // round-to-nearest-even (inputs finite)
    return (unsigned short)(u >> 16);
}

__global__ void __launch_bounds__(1024)
convert_convw(const float* __restrict__ src, unsigned short* __restrict__ dst) {
    int i = blockIdx.x * 1024 + threadIdx.x;
    if (i < 512 * 1200) dst[i] = f2bf_rne(src[i]);
}

extern "C" __global__ void __launch_bounds__(512, 2)
pcnn_fused(const int* __restrict__ tokens, const int* __restrict__ pf1,
           const int* __restrict__ pf2, const int* __restrict__ epos,
           const float* __restrict__ wordvec,
           const float* __restrict__ pf1e,
           const float* __restrict__ pf2e,
           const unsigned short* __restrict__ convwb,   // bf16 [512][1200] in ws
           const float* __restrict__ convb,
           const float* __restrict__ outw,
           const float* __restrict__ outb,
           float* __restrict__ out)
{
    extern __shared__ char smem[];
    unsigned short* xl = (unsigned short*)smem;          // 130*424 ush = 110240 B
    float* feat = (float*)(smem + 110240);               // 1536 f = 6144 B
    float* red  = (float*)(smem + 110240 + 6144);        // 512 f  = 2048 B
    int*   idx  = (int*)(smem + 110240 + 6144 + 2048);   // 3*128  = 1536 B

    const int n    = blockIdx.x;
    const int tid  = threadIdx.x;
    const int lane = tid & 63;
    const int wv   = tid >> 6;

    // preload indices + zero pad rows 128/129 (t=126,127 windows read zeros)
    if (tid < 128) {
        int base = n * 128 + tid;
        idx[tid]       = tokens[base];
        idx[128 + tid] = pf1[base];
        idx[256 + tid] = pf2[base];
    }
    {
        const short8 z8 = {0, 0, 0, 0, 0, 0, 0, 0};
        short8* dst = (short8*)xl;                       // 53 short8 per row
        for (int i = tid; i < 100; i += 512) {
            int row = 128 + i / 50, c = i % 50;
            dst[row * 53 + c] = z8;
        }
    }
    __syncthreads();

    // ---- flat gather + fp32->bf16: all iterations independent ----
    {
        const float2* wv2 = (const float2*)wordvec;      // 150 float2 per row
        const float2* p12 = (const float2*)pf1e;         // 25 float2 per row
        const float2* p22 = (const float2*)pf2e;
        #pragma unroll 4
        for (int i = tid; i < 128 * 150; i += 512) {     // word part
            int row = i / 150, c = i - row * 150;
            float2 v = wv2[(long)idx[row] * 150 + c];
            *(ushort2*)(xl + row * XSTRIDE + 2 * c) =
                make_ushort2(f2bf_rne(v.x), f2bf_rne(v.y));
        }
        #pragma unroll 4
        for (int i = tid; i < 128 * 25; i += 512) {      // pf1 + pf2 parts
            int row = i / 25, c = i - row * 25;
            float2 v = p12[idx[128 + row] * 25 + c];
            *(ushort2*)(xl + row * XSTRIDE + 300 + 2 * c) =
                make_ushort2(f2bf_rne(v.x), f2bf_rne(v.y));
            float2 w = p22[idx[256 + row] * 25 + c];
            *(ushort2*)(xl + row * XSTRIDE + 350 + 2 * c) =
                make_ushort2(f2bf_rne(w.x), f2bf_rne(w.y));
        }
    }
    __syncthreads();

    // ---- conv GEMM: C[128 t x 512 f]; wave wv owns f in [64wv, 64wv+64) ----
    // A[t][k] = xl[t + k/400][k%400]; B^T row f (bf16 in ws). No barriers in
    // the K-loop; B prefetched one iteration ahead in registers.
    const int col = lane & 15;   // A row-in-tile / B row-in-tile / C col
    const int kq  = lane >> 4;   // k-quad: k offset 8*kq; C row = 4*kq + r

    const floatx4 fz = {0.f, 0.f, 0.f, 0.f};
    floatx4 acc[8][4];   // [mt][jt]
    #pragma unroll
    for (int mt = 0; mt < 8; ++mt)
        #pragma unroll
        for (int jt = 0; jt < 4; ++jt) acc[mt][jt] = fz;

    int ck   = kq * 8;                       // k mod 400 for this lane
    int aoff = col * XSTRIDE + kq * 8;       // elem offset of A frag (row mt=0)
    const unsigned short* bptr = convwb + (wv * 64 + col) * 1200 + kq * 8;

    short8 bn[4];                            // prefetched B frags (kt)
    #pragma unroll
    for (int jt = 0; jt < 4; ++jt)
        bn[jt] = *(const short8*)(bptr + jt * (16 * 1200));

    #pragma unroll 1
    for (int kt = 0; kt < 37; ++kt) {        // K = 37*32 + 16 remainder
        short8 a[8], b[4];
        #pragma unroll
        for (int jt = 0; jt < 4; ++jt) b[jt] = bn[jt];
        if (kt < 36) {                       // prefetch kt+1 (wave-uniform)
            const unsigned short* bp2 = bptr + 32;
            #pragma unroll
            for (int jt = 0; jt < 4; ++jt)
                bn[jt] = *(const short8*)(bp2 + jt * (16 * 1200));
        }
        #pragma unroll
        for (int mt = 0; mt < 8; ++mt)
            a[mt] = *(const short8*)(xl + aoff + mt * (16 * XSTRIDE));
        #pragma unroll
        for (int mt = 0; mt < 8; ++mt)
            #pragma unroll
            for (int jt = 0; jt < 4; ++jt)
                acc[mt][jt] = __builtin_amdgcn_mfma_f32_16x16x32_bf16(
                    a[mt], b[jt], acc[mt][jt], 0, 0, 0);
        ck += 32; aoff += 32; bptr += 32;
        if (ck >= 400) { ck -= 400; aoff += XSTRIDE - 400; }
    }
    {   // remainder k0=1184..1199: only kq<2 lanes carry real k
        const short8 z8 = {0, 0, 0, 0, 0, 0, 0, 0};
        short8 a[8], b[4];
        #pragma unroll
        for (int mt = 0; mt < 8; ++mt) a[mt] = z8;
        #pragma unroll
        for (int jt = 0; jt < 4; ++jt) b[jt] = z8;
        if (kq < 2) {
            #pragma unroll
            for (int mt = 0; mt < 8; ++mt)
                a[mt] = *(const short8*)(xl + aoff + mt * (16 * XSTRIDE));
            #pragma unroll
            for (int jt = 0; jt < 4; ++jt)
                b[jt] = *(const short8*)(bptr + jt * (16 * 1200));
        }
        #pragma unroll
        for (int mt = 0; mt < 8; ++mt)
            #pragma unroll
            for (int jt = 0; jt < 4; ++jt)
                acc[mt][jt] = __builtin_amdgcn_mfma_f32_16x16x32_bf16(
                    a[mt], b[jt], acc[mt][jt], 0, 0, 0);
    }

    // ---- epilogue: pool raw acc over 3 segments, reduce across kq lanes ----
    const int p1 = epos[2 * n], p2 = epos[2 * n + 1];
    #pragma unroll
    for (int jt = 0; jt < 4; ++jt) {
        float m0 = -1e30f, m1 = -1e30f, m2 = -1e30f;
        #pragma unroll
        for (int mt = 0; mt < 8; ++mt) {
            #pragma unroll
            for (int r = 0; r < 4; ++r) {
                int t = mt * 16 + kq * 4 + r;   // C/D row mapping
                float v = acc[mt][jt][r];
                if (t < LPV) {
                    if (t <= p1) m0 = fmaxf(m0, v);
                    if (t >= p1 && t <= p2) m1 = fmaxf(m1, v);
                    if (t >= p2) m2 = fmaxf(m2, v);
                }
            }
        }
        // lanes sharing col differ in kq (xor 16, 32): reduce t-coverage
        m0 = fmaxf(m0, __shfl_xor(m0, 16)); m0 = fmaxf(m0, __shfl_xor(m0, 32));
        m1 = fmaxf(m1, __shfl_xor(m1, 16)); m1 = fmaxf(m1, __shfl_xor(m1, 32));
        m2 = fmaxf(m2, __shfl_xor(m2, 16)); m2 = fmaxf(m2, __shfl_xor(m2, 32));
        if (kq == 0) {
            int f = wv * 64 + jt * 16 + col;
            float bias = convb[f];
            // tanh monotonic: max(tanh(x+b)) == tanh(max(x)+b); segs nonempty
            feat[3 * f + 0] = tanhf(m0 + bias);
            feat[3 * f + 1] = tanhf(m1 + bias);
            feat[3 * f + 2] = tanhf(m2 + bias);
        }
    }
    __syncthreads();

    // ---- out GEMM: out[n,c] = feat . out_w[:,c] + out_b[c], fp32 ----
    {
        int c = tid & 63;
        int chunk = tid >> 6;          // 8 chunks x 192 j
        float partial = 0.f;
        if (c < NC) {
            int j0 = chunk * 192;
            #pragma unroll 4
            for (int j = j0; j < j0 + 192; ++j)
                partial += feat[j] * outw[j * 53 + c];
        }
        red[tid] = partial;
        __syncthreads();
        if (tid < NC) {
            float s = outb[tid];
            #pragma unroll
            for (int ch = 0; ch < 8; ++ch) s += red[ch * 64 + tid];
            out[n * 53 + tid] = s;
        }
    }
}

extern "C" void kernel_launch(void* const* d_in, const int* in_sizes, int n_in,
                              void* d_out, int out_size, void* d_ws, size_t ws_size,
                              hipStream_t stream) {
    (void)in_sizes; (void)n_in; (void)ws_size; (void)out_size;
    const int* tokens = (const int*)d_in[0];
    const int* pf1    = (const int*)d_in[1];
    const int* pf2    = (const int*)d_in[2];
    const int* epos   = (const int*)d_in[3];
    const float* wordvec = (const float*)d_in[4];
    const float* pf1e    = (const float*)d_in[5];
    const float* pf2e    = (const float*)d_in[6];
    const float* convw   = (const float*)d_in[7];
    const float* convb   = (const float*)d_in[8];
    const float* outw    = (const float*)d_in[9];
    const float* outb    = (const float*)d_in[10];
    float* out = (float*)d_out;

    unsigned short* convwb = (unsigned short*)d_ws;   // 512*1200 bf16 = 1.23 MB

    convert_convw<<<dim3(600), dim3(1024), 0, stream>>>(convw, convwb);

    const size_t lds_bytes = 110240 + 6144 + 2048 + 1536;   // 119968
    pcnn_fused<<<dim3(1024), dim3(512), lds_bytes, stream>>>(
        tokens, pf1, pf2, epos, wordvec, pf1e, pf2e, convwb,
        convb, outw, outb, out);
}